// Round 10
// baseline (187.391 us; speedup 1.0000x reference)
//
#include <hip/hip_runtime.h>
#include <hip/hip_bf16.h>

// Local-window attention, B=32 S=1024(16x64) H=8 D=384/8=48, window 7x11.
// R10: effective BK=64 — two BK=32 tiles per barrier pair (4 LDS buffers,
//      64KB): stage pair s+1 -> vmcnt(8) -> barrier -> compute pair s
//      (32 MFMA, 16 ds_read per wave) -> lgkmcnt(0) -> barrier. 6 super-iters
//      instead of 12 -> half the barrier/stage serialization. Staging/swizzle/
//      read code byte-identical to the R2-verified BK=32 version. +setprio
//      around MFMA cluster. attn_mfma / cvt / transpose unchanged (passing).

typedef __attribute__((ext_vector_type(8))) unsigned short ushort8;
typedef __attribute__((ext_vector_type(4))) unsigned short ushort4v;
typedef __attribute__((ext_vector_type(8))) short short8v;
typedef __attribute__((ext_vector_type(4))) float floatx4;

__device__ __forceinline__ float bf2f(unsigned short u) {
  union { unsigned int i; float f; } x;
  x.i = ((unsigned int)u) << 16;
  return x.f;
}

__device__ __forceinline__ unsigned short f2bu(float f) {
  union { float f; unsigned int i; } x;
  x.f = f;
  unsigned int lsb = (x.i >> 16) & 1u;
  x.i += 0x7FFFu + lsb;  // RNE
  return (unsigned short)(x.i >> 16);
}

__device__ __forceinline__ void gload_lds16(const void* g, void* l) {
  __builtin_amdgcn_global_load_lds(
      (const __attribute__((address_space(1))) unsigned int*)g,
      (__attribute__((address_space(3))) unsigned int*)l, 16, 0, 0);
}

// ---------------- K0a: f32 -> bf16 ----------------
__global__ __launch_bounds__(256) void cvt_f32_bf16(
    const float4* __restrict__ in, ushort4v* __restrict__ out, int n4) {
  const int i = blockIdx.x * 256 + threadIdx.x;
  if (i < n4) {
    const float4 v = in[i];
    ushort4v o;
    o[0] = f2bu(v.x); o[1] = f2bu(v.y); o[2] = f2bu(v.z); o[3] = f2bu(v.w);
    out[i] = o;
  }
}

// ---------------- K0b/c: transpose f32 [R][C] -> bf16 [C][R] ----------------
__global__ __launch_bounds__(256) void transpose_cvt(
    const float* __restrict__ in, unsigned short* __restrict__ out, int R, int C) {
  __shared__ float t[32][33];
  const int c0 = blockIdx.x * 32, r0 = blockIdx.y * 32;
  const int tx = threadIdx.x, ty = threadIdx.y;
  #pragma unroll
  for (int rr = ty; rr < 32; rr += 8) t[rr][tx] = in[(size_t)(r0 + rr) * C + c0 + tx];
  __syncthreads();
  #pragma unroll
  for (int rr = ty; rr < 32; rr += 8)
    out[(size_t)(c0 + rr) * R + r0 + tx] = f2bu(t[tx][rr]);
}

// ---------------- MFMA GEMM, 2-tiles-per-barrier (eff. BK=64) ----------------
// 128x128 tile, 4 x BK=32 LDS buffers. Super-iter s: stage tiles {2s+2,2s+3}
// into idle buf pair -> vmcnt(8) -> barrier -> compute tiles {2s,2s+1}
// -> lgkmcnt(0) -> barrier. XOR-16 swizzle both sides (R2-verified).
// Chunked XCD swizzle on flattened bid (nwg % 8 == 0 for both launches).
template <int MODE>
__global__ __launch_bounds__(256) void gemm_mfma(
    const unsigned short* __restrict__ A,   // [M][384] bf16
    const unsigned short* __restrict__ Bt,  // [N][384] bf16 (= B^T)
    const float* __restrict__ bias, float* __restrict__ outf,
    unsigned short* __restrict__ qws, unsigned short* __restrict__ kws,
    unsigned short* __restrict__ vtws)
{
  __shared__ unsigned short As[4][128 * 32];
  __shared__ unsigned short Bs[4][128 * 32];
  const int tid = threadIdx.x;
  const int lane = tid & 63, w = tid >> 6;
  const int wm = w & 1, wn = w >> 1;

  // chunked XCD swizzle: contiguous runs of nwg/8 blocks per XCD
  const int nbx = gridDim.x;
  const int nwg = nbx * gridDim.y;
  const int bid = blockIdx.y * nbx + blockIdx.x;
  const int swz = (bid & 7) * (nwg >> 3) + (bid >> 3);
  const int n0 = (swz % nbx) * 128;
  const int m0 = (swz / nbx) * 128;

  floatx4 acc[4][4];
  #pragma unroll
  for (int mi = 0; mi < 4; ++mi)
    #pragma unroll
    for (int ni = 0; ni < 4; ++ni)
      acc[mi][ni] = (floatx4){0.f, 0.f, 0.f, 0.f};

  const int srow = w * 16 + (lane >> 2);
  const int kslot16 = (lane & 3) * 16;

  auto STAGE = [&](int buf, int k0) {
    #pragma unroll
    for (int c = 0; c < 2; ++c) {
      const int r = c * 64 + srow;
      const int kb = kslot16 ^ ((r & 3) << 4);
      gload_lds16((const char*)A + (size_t)(m0 + r) * 768 + k0 * 2 + kb,
                  (char*)As[buf] + c * 4096 + w * 1024);
      gload_lds16((const char*)Bt + (size_t)(n0 + r) * 768 + k0 * 2 + kb,
                  (char*)Bs[buf] + c * 4096 + w * 1024);
    }
  };

  auto COMPUTE = [&](int buf) {
    short8v a[4], b[4];
    const int kgb = (lane >> 4) * 16;
    #pragma unroll
    for (int mi = 0; mi < 4; ++mi) {
      const int r = wm * 64 + mi * 16 + (lane & 15);
      a[mi] = *reinterpret_cast<const short8v*>(
          (const char*)As[buf] + r * 64 + (kgb ^ ((r & 3) << 4)));
    }
    #pragma unroll
    for (int ni = 0; ni < 4; ++ni) {
      const int r = wn * 64 + ni * 16 + (lane & 15);
      b[ni] = *reinterpret_cast<const short8v*>(
          (const char*)Bs[buf] + r * 64 + (kgb ^ ((r & 3) << 4)));
    }
    #pragma unroll
    for (int mi = 0; mi < 4; ++mi)
      #pragma unroll
      for (int ni = 0; ni < 4; ++ni)
        acc[mi][ni] = __builtin_amdgcn_mfma_f32_16x16x32_bf16(
            a[mi], b[ni], acc[mi][ni], 0, 0, 0);
  };

  STAGE(0, 0);
  STAGE(1, 32);

  #pragma unroll
  for (int s = 0; s < 6; ++s) {
    const int rb = (s & 1) * 2;  // read bufs rb, rb+1 (tiles 2s, 2s+1)
    const int sb = rb ^ 2;       // stage bufs (tiles 2s+2, 2s+3)
    if (s < 5) {
      STAGE(sb, (2 * s + 2) * 32);
      STAGE(sb + 1, (2 * s + 3) * 32);
      asm volatile("s_waitcnt vmcnt(8)" ::: "memory");  // read-pair loads done
    } else {
      asm volatile("s_waitcnt vmcnt(0)" ::: "memory");
    }
    __builtin_amdgcn_s_barrier();          // read-pair visible to all waves
    __builtin_amdgcn_s_setprio(1);
    COMPUTE(rb);
    COMPUTE(rb + 1);
    __builtin_amdgcn_s_setprio(0);
    asm volatile("s_waitcnt lgkmcnt(0)" ::: "memory");  // this wave's reads done
    __builtin_amdgcn_s_barrier();          // all waves done with read-pair bufs
  }

  const int col_l = lane & 15;
  const int row_l = (lane >> 4) * 4;

  if (MODE == 0) {
    const float QSCALE = 0.14433756729740643f;  // 1/sqrt(48)
    #pragma unroll
    for (int ni = 0; ni < 4; ++ni) {
      const int cg = n0 + wn * 64 + ni * 16 + col_l;
      const int which = cg / 384;
      const int rem = cg - which * 384;
      const int h = rem / 48;
      const int d = rem - h * 48;
      const float scale = (which == 0) ? QSCALE : 1.f;
      #pragma unroll
      for (int mi = 0; mi < 4; ++mi) {
        #pragma unroll
        for (int reg = 0; reg < 4; ++reg) {
          const int r = m0 + wm * 64 + mi * 16 + row_l + reg;
          const int bb = r >> 10, s = r & 1023;
          const unsigned short val = f2bu(acc[mi][ni][reg] * scale);
          if (which == 0)
            qws[(((size_t)(bb * 8 + h)) * 1024 + s) * 48 + d] = val;
          else if (which == 1)
            kws[(((size_t)(bb * 8 + h)) * 1024 + s) * 48 + d] = val;
          else  // V stored TRANSPOSED: vt[bh][d][s]
            vtws[(((size_t)(bb * 8 + h)) * 48 + d) * 1024 + s] = val;
        }
      }
    }
  } else {
    #pragma unroll
    for (int ni = 0; ni < 4; ++ni) {
      const int cg = n0 + wn * 64 + ni * 16 + col_l;
      const float bv = bias[cg];
      #pragma unroll
      for (int mi = 0; mi < 4; ++mi) {
        #pragma unroll
        for (int reg = 0; reg < 4; ++reg) {
          const int r = m0 + wm * 64 + mi * 16 + row_l + reg;
          outf[(size_t)r * 384 + cg] = acc[mi][ni][reg] + bv;
        }
      }
    }
  }
}

// ---------------- K2: MFMA local attention (unchanged from R6/R7) ----------------
__global__ __launch_bounds__(64) void attn_mfma(
    const unsigned short* __restrict__ qws,  // [bh][1024][48]
    const unsigned short* __restrict__ kws,  // [bh][1024][48]
    const unsigned short* __restrict__ vt,   // [bh][48][1024]
    unsigned short* __restrict__ attn_out)   // [b*1024][384] bf16
{
  __shared__ unsigned short plds[64 * 72];  // stride 144B: 16B-aligned rows

  const int task = ((blockIdx.x & 7) << 9) | (blockIdx.x >> 3);  // 4096%8==0
  const int i  = task & 15;
  const int bh = task >> 4;
  const int lane = threadIdx.x;
  const int ql = lane & 15;   // q local (also A-frag row local)
  const int g  = lane >> 4;   // 8-elem k-slice group

  const unsigned short* qbase = qws + (size_t)bh * 1024 * 48;
  const unsigned short* kbase = kws + (size_t)bh * 1024 * 48;
  const unsigned short* vbase = vt  + (size_t)bh * 48 * 1024;

  const short8v zfrag = (short8v){0, 0, 0, 0, 0, 0, 0, 0};

  // Q fragments [qt][kstep]; D=48 zero-padded to 64 (kstep1, g>=2 -> 0)
  short8v qf[4][2];
  #pragma unroll
  for (int qt = 0; qt < 4; ++qt) {
    const unsigned short* qrow = qbase + (size_t)(i * 64 + qt * 16 + ql) * 48;
    qf[qt][0] = *reinterpret_cast<const short8v*>(qrow + 8 * g);
    qf[qt][1] = (g < 2) ? *reinterpret_cast<const short8v*>(qrow + 32 + 8 * g)
                        : zfrag;
  }

  floatx4 ot[3][4];  // O^T accum [dtile][qtile], d = 16dt+4g+reg, q = qt*16+ql
  #pragma unroll
  for (int dt = 0; dt < 3; ++dt)
    #pragma unroll
    for (int qt = 0; qt < 4; ++qt)
      ot[dt][qt] = (floatx4){0.f, 0.f, 0.f, 0.f};
  float mreg[4] = {-INFINITY, -INFINITY, -INFINITY, -INFINITY};
  float lreg[4] = {0.f, 0.f, 0.f, 0.f};

  const int ki0 = (i - 3 < 0) ? 0 : i - 3;
  const int ki1 = (i + 3 > 15) ? 15 : i + 3;

  for (int ki = ki0; ki <= ki1; ++ki) {
    // K fragments [kt][kstep]
    short8v kf[4][2];
    #pragma unroll
    for (int kt = 0; kt < 4; ++kt) {
      const unsigned short* krow = kbase + (size_t)(ki * 64 + kt * 16 + ql) * 48;
      kf[kt][0] = *reinterpret_cast<const short8v*>(krow + 8 * g);
      kf[kt][1] = (g < 2) ? *reinterpret_cast<const short8v*>(krow + 32 + 8 * g)
                          : zfrag;
    }
    // V^T fragments [dt][chunk]: lane holds V^T[16dt+ql][32c+8g .. +7]
    short8v vf[3][2];
    #pragma unroll
    for (int dt = 0; dt < 3; ++dt)
      #pragma unroll
      for (int c = 0; c < 2; ++c)
        vf[dt][c] = *reinterpret_cast<const short8v*>(
            vbase + (size_t)(16 * dt + ql) * 1024 + ki * 64 + 32 * c + 8 * g);

    // per q-tile: QK^T, mask, g-group-reduced online softmax, P -> LDS
    #pragma unroll
    for (int qt = 0; qt < 4; ++qt) {
      floatx4 s[4];
      #pragma unroll
      for (int kt = 0; kt < 4; ++kt) {
        s[kt] = __builtin_amdgcn_mfma_f32_16x16x32_bf16(
            kf[kt][0], qf[qt][0], (floatx4){0.f, 0.f, 0.f, 0.f}, 0, 0, 0);
        s[kt] = __builtin_amdgcn_mfma_f32_16x16x32_bf16(
            kf[kt][1], qf[qt][1], s[kt], 0, 0, 0);
      }
      const int qcol = qt * 16 + ql;
      float mt = -INFINITY;
      #pragma unroll
      for (int kt = 0; kt < 4; ++kt) {
        #pragma unroll
        for (int r = 0; r < 4; ++r) {
          const int delta = kt * 16 + 4 * g + r - qcol;
          const bool ok = (delta <= 5) && (delta >= -5);
          s[kt][r] = ok ? s[kt][r] : -INFINITY;
          mt = fmaxf(mt, s[kt][r]);
        }
      }
      // reduce max across the 4 lanes sharing this q (lane bits 4-5)
      mt = fmaxf(mt, __shfl_xor(mt, 16, 64));
      mt = fmaxf(mt, __shfl_xor(mt, 32, 64));
      const float mnew = fmaxf(mreg[qt], mt);  // finite: own column in window
      const float corr = __expf(mreg[qt] - mnew);
      mreg[qt] = mnew;
      float ps = 0.f;
      #pragma unroll
      for (int kt = 0; kt < 4; ++kt) {
        #pragma unroll
        for (int r = 0; r < 4; ++r) {
          const float p = __expf(s[kt][r] - mnew);  // masked -> exp(-inf)=0
          s[kt][r] = p;
          ps += p;
        }
      }
      // reduce sum across the g-group
      ps += __shfl_xor(ps, 16, 64);
      ps += __shfl_xor(ps, 32, 64);
      lreg[qt] = lreg[qt] * corr + ps;
      #pragma unroll
      for (int dt = 0; dt < 3; ++dt) {
        ot[dt][qt][0] *= corr; ot[dt][qt][1] *= corr;
        ot[dt][qt][2] *= corr; ot[dt][qt][3] *= corr;
      }
      // pack P (bf16), write C-layout rows: plds[q][kt*16 + 4g .. +3]
      #pragma unroll
      for (int kt = 0; kt < 4; ++kt) {
        uint2 pk;
        pk.x = (unsigned int)f2bu(s[kt][0]) | ((unsigned int)f2bu(s[kt][1]) << 16);
        pk.y = (unsigned int)f2bu(s[kt][2]) | ((unsigned int)f2bu(s[kt][3]) << 16);
        *reinterpret_cast<uint2*>(&plds[(qt * 16 + ql) * 72 + kt * 16 + 4 * g]) = pk;
      }
    }

    // PV: O^T[dt][qt] += V^T · P^T  (B-frag: lane reads plds[q][32c+8g .. +7])
    #pragma unroll
    for (int qt = 0; qt < 4; ++qt) {
      #pragma unroll
      for (int c = 0; c < 2; ++c) {
        const short8v pf = *reinterpret_cast<const short8v*>(
            &plds[(qt * 16 + ql) * 72 + 32 * c + 8 * g]);
        #pragma unroll
        for (int dt = 0; dt < 3; ++dt)
          ot[dt][qt] = __builtin_amdgcn_mfma_f32_16x16x32_bf16(
              vf[dt][c], pf, ot[dt][qt], 0, 0, 0);
      }
    }
  }

  // epilogue: normalize, store O^T -> attn_out[(b, i*64+q)][h*48 + d]
  const int b = bh >> 3, h = bh & 7;
  #pragma unroll
  for (int qt = 0; qt < 4; ++qt) {
    const float inv = 1.0f / lreg[qt];
    unsigned short* orow =
        attn_out + (size_t)(b * 1024 + i * 64 + qt * 16 + ql) * 384 + h * 48;
    #pragma unroll
    for (int dt = 0; dt < 3; ++dt) {
      const int d0 = 16 * dt + 4 * g;
      unsigned int w0 = (unsigned int)f2bu(ot[dt][qt][0] * inv) |
                        ((unsigned int)f2bu(ot[dt][qt][1] * inv) << 16);
      unsigned int w1 = (unsigned int)f2bu(ot[dt][qt][2] * inv) |
                        ((unsigned int)f2bu(ot[dt][qt][3] * inv) << 16);
      *reinterpret_cast<unsigned int*>(orow + d0)     = w0;
      *reinterpret_cast<unsigned int*>(orow + d0 + 2) = w1;
    }
  }
}

extern "C" void kernel_launch(void* const* d_in, const int* in_sizes, int n_in,
                              void* d_out, int out_size, void* d_ws, size_t ws_size,
                              hipStream_t stream) {
  const float* x      = (const float*)d_in[0];
  const float* w_qkv  = (const float*)d_in[1];
  const float* w_proj = (const float*)d_in[2];
  const float* b_proj = (const float*)d_in[3];
  // d_in[4] (mask) unused: window is analytic (|di|<=3, |dj|<=5)

  const size_t T = 25165824;  // 32768*384*2 bytes
  char* ws = (char*)d_ws;
  unsigned short* xb    = (unsigned short*)ws;            // aliased with attn_out
  unsigned short* qws   = (unsigned short*)(ws + T);
  unsigned short* kws   = (unsigned short*)(ws + 2 * T);
  unsigned short* vtws  = (unsigned short*)(ws + 3 * T);  // [bh][48][1024]
  unsigned short* wqkvT = (unsigned short*)(ws + 4 * T);
  unsigned short* wpT   = (unsigned short*)(ws + 4 * T + 884736);
  unsigned short* attn_out = xb;  // xb dead after K1
  float* out = (float*)d_out;

  // K0: conversions
  cvt_f32_bf16<<<12288, 256, 0, stream>>>((const float4*)x, (ushort4v*)xb, 3145728);
  transpose_cvt<<<dim3(36, 12), dim3(32, 8), 0, stream>>>(w_qkv, wqkvT, 384, 1152);
  transpose_cvt<<<dim3(12, 12), dim3(32, 8), 0, stream>>>(w_proj, wpT, 384, 384);

  // K1: qkv GEMM (M=32768, K=384, N=1152) -> q/k [bh][s][48], v^T [bh][48][s]
  gemm_mfma<0><<<dim3(9, 256), 256, 0, stream>>>(xb, wqkvT, nullptr, nullptr,
                                                 qws, kws, vtws);
  // K2: MFMA local attention -> attn_out bf16 [B*S, 384]
  attn_mfma<<<dim3(4096), 64, 0, stream>>>(qws, kws, vtws, attn_out);
  // K3: out = attn_out @ w_proj + bias (N=384), f32 out
  gemm_mfma<1><<<dim3(3, 256), 256, 0, stream>>>(attn_out, wpT, b_proj, out,
                                                 nullptr, nullptr, nullptr);
}

// Round 11
// 156.068 us; speedup vs baseline: 1.2007x; 1.2007x over previous
//
#include <hip/hip_runtime.h>
#include <hip/hip_bf16.h>

// Local-window attention, B=32 S=1024(16x64) H=8 D=384/8=48, window 7x11.
// R11: fix K1's hidden epilogue tax — the V^T scatter (2B x 64 lanes across
//      16 distant rows per store instr) cost ~30-40us since R6. V-blocks
//      (n0>=768, uniform) now transpose their C-tile through LDS (stride-136
//      bf16 tile aliasing the dead staging smem) and write vt rows coalesced
//      (16B chunks). K-loop / q,k epilogue / attn / K3 identical to R10.

typedef __attribute__((ext_vector_type(8))) unsigned short ushort8;
typedef __attribute__((ext_vector_type(4))) unsigned short ushort4v;
typedef __attribute__((ext_vector_type(8))) short short8v;
typedef __attribute__((ext_vector_type(4))) float floatx4;

__device__ __forceinline__ float bf2f(unsigned short u) {
  union { unsigned int i; float f; } x;
  x.i = ((unsigned int)u) << 16;
  return x.f;
}

__device__ __forceinline__ unsigned short f2bu(float f) {
  union { float f; unsigned int i; } x;
  x.f = f;
  unsigned int lsb = (x.i >> 16) & 1u;
  x.i += 0x7FFFu + lsb;  // RNE
  return (unsigned short)(x.i >> 16);
}

__device__ __forceinline__ void gload_lds16(const void* g, void* l) {
  __builtin_amdgcn_global_load_lds(
      (const __attribute__((address_space(1))) unsigned int*)g,
      (__attribute__((address_space(3))) unsigned int*)l, 16, 0, 0);
}

// ---------------- K0a: f32 -> bf16 ----------------
__global__ __launch_bounds__(256) void cvt_f32_bf16(
    const float4* __restrict__ in, ushort4v* __restrict__ out, int n4) {
  const int i = blockIdx.x * 256 + threadIdx.x;
  if (i < n4) {
    const float4 v = in[i];
    ushort4v o;
    o[0] = f2bu(v.x); o[1] = f2bu(v.y); o[2] = f2bu(v.z); o[3] = f2bu(v.w);
    out[i] = o;
  }
}

// ---------------- K0b/c: transpose f32 [R][C] -> bf16 [C][R] ----------------
__global__ __launch_bounds__(256) void transpose_cvt(
    const float* __restrict__ in, unsigned short* __restrict__ out, int R, int C) {
  __shared__ float t[32][33];
  const int c0 = blockIdx.x * 32, r0 = blockIdx.y * 32;
  const int tx = threadIdx.x, ty = threadIdx.y;
  #pragma unroll
  for (int rr = ty; rr < 32; rr += 8) t[rr][tx] = in[(size_t)(r0 + rr) * C + c0 + tx];
  __syncthreads();
  #pragma unroll
  for (int rr = ty; rr < 32; rr += 8)
    out[(size_t)(c0 + rr) * R + r0 + tx] = f2bu(t[tx][rr]);
}

// ---------------- MFMA GEMM, 2-tiles-per-barrier (eff. BK=64) ----------------
// Same K-loop as R10. Epilogue: q/k blocks scatter as before; V blocks
// (uniform per block since 384|768) transpose the C-tile through LDS and
// write vt[(bb*8+h)*48+d][m0..m0+127] as coalesced 16B chunks.
template <int MODE>
__global__ __launch_bounds__(256) void gemm_mfma(
    const unsigned short* __restrict__ A,   // [M][384] bf16
    const unsigned short* __restrict__ Bt,  // [N][384] bf16 (= B^T)
    const float* __restrict__ bias, float* __restrict__ outf,
    unsigned short* __restrict__ qws, unsigned short* __restrict__ kws,
    unsigned short* __restrict__ vtws)
{
  __shared__ unsigned short smem[32768];  // 64KB: staging bufs / transpose tile
  const int tid = threadIdx.x;
  const int lane = tid & 63, w = tid >> 6;
  const int wm = w & 1, wn = w >> 1;

  // chunked XCD swizzle: contiguous runs of nwg/8 blocks per XCD
  const int nbx = gridDim.x;
  const int nwg = nbx * gridDim.y;
  const int bid = blockIdx.y * nbx + blockIdx.x;
  const int swz = (bid & 7) * (nwg >> 3) + (bid >> 3);
  const int n0 = (swz % nbx) * 128;
  const int m0 = (swz / nbx) * 128;

  floatx4 acc[4][4];
  #pragma unroll
  for (int mi = 0; mi < 4; ++mi)
    #pragma unroll
    for (int ni = 0; ni < 4; ++ni)
      acc[mi][ni] = (floatx4){0.f, 0.f, 0.f, 0.f};

  const int srow = w * 16 + (lane >> 2);
  const int kslot16 = (lane & 3) * 16;

  auto ASB = [&](int buf) -> unsigned short* { return smem + buf * 4096; };
  auto BSB = [&](int buf) -> unsigned short* { return smem + 16384 + buf * 4096; };

  auto STAGE = [&](int buf, int k0) {
    #pragma unroll
    for (int c = 0; c < 2; ++c) {
      const int r = c * 64 + srow;
      const int kb = kslot16 ^ ((r & 3) << 4);
      gload_lds16((const char*)A + (size_t)(m0 + r) * 768 + k0 * 2 + kb,
                  (char*)ASB(buf) + c * 4096 + w * 1024);
      gload_lds16((const char*)Bt + (size_t)(n0 + r) * 768 + k0 * 2 + kb,
                  (char*)BSB(buf) + c * 4096 + w * 1024);
    }
  };

  auto COMPUTE = [&](int buf) {
    short8v a[4], b[4];
    const int kgb = (lane >> 4) * 16;
    #pragma unroll
    for (int mi = 0; mi < 4; ++mi) {
      const int r = wm * 64 + mi * 16 + (lane & 15);
      a[mi] = *reinterpret_cast<const short8v*>(
          (const char*)ASB(buf) + r * 64 + (kgb ^ ((r & 3) << 4)));
    }
    #pragma unroll
    for (int ni = 0; ni < 4; ++ni) {
      const int r = wn * 64 + ni * 16 + (lane & 15);
      b[ni] = *reinterpret_cast<const short8v*>(
          (const char*)BSB(buf) + r * 64 + (kgb ^ ((r & 3) << 4)));
    }
    #pragma unroll
    for (int mi = 0; mi < 4; ++mi)
      #pragma unroll
      for (int ni = 0; ni < 4; ++ni)
        acc[mi][ni] = __builtin_amdgcn_mfma_f32_16x16x32_bf16(
            a[mi], b[ni], acc[mi][ni], 0, 0, 0);
  };

  STAGE(0, 0);
  STAGE(1, 32);

  #pragma unroll
  for (int s = 0; s < 6; ++s) {
    const int rb = (s & 1) * 2;  // read bufs rb, rb+1 (tiles 2s, 2s+1)
    const int sb = rb ^ 2;       // stage bufs (tiles 2s+2, 2s+3)
    if (s < 5) {
      STAGE(sb, (2 * s + 2) * 32);
      STAGE(sb + 1, (2 * s + 3) * 32);
      asm volatile("s_waitcnt vmcnt(8)" ::: "memory");  // read-pair loads done
    } else {
      asm volatile("s_waitcnt vmcnt(0)" ::: "memory");
    }
    __builtin_amdgcn_s_barrier();          // read-pair visible to all waves
    __builtin_amdgcn_s_setprio(1);
    COMPUTE(rb);
    COMPUTE(rb + 1);
    __builtin_amdgcn_s_setprio(0);
    asm volatile("s_waitcnt lgkmcnt(0)" ::: "memory");  // this wave's reads done
    __builtin_amdgcn_s_barrier();          // all waves done with read-pair bufs
  }

  const int col_l = lane & 15;
  const int row_l = (lane >> 4) * 4;

  if (MODE == 0) {
    const float QSCALE = 0.14433756729740643f;  // 1/sqrt(48)
    const int which = n0 / 384;  // uniform per block (384 | 128*{0,3,6})
    if (which < 2) {
      // q / k: original scatter (32B-segment stores)
      unsigned short* dstb = (which == 0) ? qws : kws;
      const float scale = (which == 0) ? QSCALE : 1.f;
      #pragma unroll
      for (int ni = 0; ni < 4; ++ni) {
        const int cg = n0 + wn * 64 + ni * 16 + col_l;
        const int rem = cg - which * 384;
        const int h = rem / 48;
        const int d = rem - h * 48;
        #pragma unroll
        for (int mi = 0; mi < 4; ++mi) {
          #pragma unroll
          for (int reg = 0; reg < 4; ++reg) {
            const int r = m0 + wm * 64 + mi * 16 + row_l + reg;
            const int bb = r >> 10, s = r & 1023;
            dstb[(((size_t)(bb * 8 + h)) * 1024 + s) * 48 + d] =
                f2bu(acc[mi][ni][reg] * scale);
          }
        }
      }
    } else {
      // V: transpose C-tile through LDS, then coalesced vt writes.
      // T[col][row], stride 136 shorts (272B: 16B-aligned rows, 2-way-banked
      // scalar writes). smem is dead here (K-loop ended with barrier).
      unsigned short* T = smem;  // needs 128*136 = 17408 shorts <= 32768
      #pragma unroll
      for (int ni = 0; ni < 4; ++ni) {
        const int col = wn * 64 + ni * 16 + col_l;
        #pragma unroll
        for (int mi = 0; mi < 4; ++mi) {
          const int rowb = wm * 64 + mi * 16 + row_l;
          #pragma unroll
          for (int reg = 0; reg < 4; ++reg)
            T[col * 136 + rowb + reg] = f2bu(acc[mi][ni][reg]);
        }
      }
      __syncthreads();
      // readback: thread = (col, half); write 8 x 16B contiguous to vt row
      const int col = tid >> 1, half = tid & 1;
      const int cg = n0 + col;
      const int rem = cg - 768;
      const int h = rem / 48, d = rem - h * 48;
      const int bb = m0 >> 10;          // whole tile in one b (m0%1024+127<1024)
      const int s0 = (m0 & 1023) + half * 64;
      unsigned short* dst =
          vtws + (((size_t)(bb * 8 + h)) * 48 + d) * 1024 + s0;
      const unsigned short* src = T + col * 136 + half * 64;
      #pragma unroll
      for (int j = 0; j < 8; ++j)
        *reinterpret_cast<ushort8*>(dst + j * 8) =
            *reinterpret_cast<const ushort8*>(src + j * 8);
    }
  } else {
    #pragma unroll
    for (int ni = 0; ni < 4; ++ni) {
      const int cg = n0 + wn * 64 + ni * 16 + col_l;
      const float bv = bias[cg];
      #pragma unroll
      for (int mi = 0; mi < 4; ++mi) {
        #pragma unroll
        for (int reg = 0; reg < 4; ++reg) {
          const int r = m0 + wm * 64 + mi * 16 + row_l + reg;
          outf[(size_t)r * 384 + cg] = acc[mi][ni][reg] + bv;
        }
      }
    }
  }
}

// ---------------- K2: MFMA local attention (unchanged from R6/R7) ----------------
__global__ __launch_bounds__(64) void attn_mfma(
    const unsigned short* __restrict__ qws,  // [bh][1024][48]
    const unsigned short* __restrict__ kws,  // [bh][1024][48]
    const unsigned short* __restrict__ vt,   // [bh][48][1024]
    unsigned short* __restrict__ attn_out)   // [b*1024][384] bf16
{
  __shared__ unsigned short plds[64 * 72];  // stride 144B: 16B-aligned rows

  const int task = ((blockIdx.x & 7) << 9) | (blockIdx.x >> 3);  // 4096%8==0
  const int i  = task & 15;
  const int bh = task >> 4;
  const int lane = threadIdx.x;
  const int ql = lane & 15;   // q local (also A-frag row local)
  const int g  = lane >> 4;   // 8-elem k-slice group

  const unsigned short* qbase = qws + (size_t)bh * 1024 * 48;
  const unsigned short* kbase = kws + (size_t)bh * 1024 * 48;
  const unsigned short* vbase = vt  + (size_t)bh * 48 * 1024;

  const short8v zfrag = (short8v){0, 0, 0, 0, 0, 0, 0, 0};

  // Q fragments [qt][kstep]; D=48 zero-padded to 64 (kstep1, g>=2 -> 0)
  short8v qf[4][2];
  #pragma unroll
  for (int qt = 0; qt < 4; ++qt) {
    const unsigned short* qrow = qbase + (size_t)(i * 64 + qt * 16 + ql) * 48;
    qf[qt][0] = *reinterpret_cast<const short8v*>(qrow + 8 * g);
    qf[qt][1] = (g < 2) ? *reinterpret_cast<const short8v*>(qrow + 32 + 8 * g)
                        : zfrag;
  }

  floatx4 ot[3][4];  // O^T accum [dtile][qtile], d = 16dt+4g+reg, q = qt*16+ql
  #pragma unroll
  for (int dt = 0; dt < 3; ++dt)
    #pragma unroll
    for (int qt = 0; qt < 4; ++qt)
      ot[dt][qt] = (floatx4){0.f, 0.f, 0.f, 0.f};
  float mreg[4] = {-INFINITY, -INFINITY, -INFINITY, -INFINITY};
  float lreg[4] = {0.f, 0.f, 0.f, 0.f};

  const int ki0 = (i - 3 < 0) ? 0 : i - 3;
  const int ki1 = (i + 3 > 15) ? 15 : i + 3;

  for (int ki = ki0; ki <= ki1; ++ki) {
    // K fragments [kt][kstep]
    short8v kf[4][2];
    #pragma unroll
    for (int kt = 0; kt < 4; ++kt) {
      const unsigned short* krow = kbase + (size_t)(ki * 64 + kt * 16 + ql) * 48;
      kf[kt][0] = *reinterpret_cast<const short8v*>(krow + 8 * g);
      kf[kt][1] = (g < 2) ? *reinterpret_cast<const short8v*>(krow + 32 + 8 * g)
                          : zfrag;
    }
    // V^T fragments [dt][chunk]: lane holds V^T[16dt+ql][32c+8g .. +7]
    short8v vf[3][2];
    #pragma unroll
    for (int dt = 0; dt < 3; ++dt)
      #pragma unroll
      for (int c = 0; c < 2; ++c)
        vf[dt][c] = *reinterpret_cast<const short8v*>(
            vbase + (size_t)(16 * dt + ql) * 1024 + ki * 64 + 32 * c + 8 * g);

    // per q-tile: QK^T, mask, g-group-reduced online softmax, P -> LDS
    #pragma unroll
    for (int qt = 0; qt < 4; ++qt) {
      floatx4 s[4];
      #pragma unroll
      for (int kt = 0; kt < 4; ++kt) {
        s[kt] = __builtin_amdgcn_mfma_f32_16x16x32_bf16(
            kf[kt][0], qf[qt][0], (floatx4){0.f, 0.f, 0.f, 0.f}, 0, 0, 0);
        s[kt] = __builtin_amdgcn_mfma_f32_16x16x32_bf16(
            kf[kt][1], qf[qt][1], s[kt], 0, 0, 0);
      }
      const int qcol = qt * 16 + ql;
      float mt = -INFINITY;
      #pragma unroll
      for (int kt = 0; kt < 4; ++kt) {
        #pragma unroll
        for (int r = 0; r < 4; ++r) {
          const int delta = kt * 16 + 4 * g + r - qcol;
          const bool ok = (delta <= 5) && (delta >= -5);
          s[kt][r] = ok ? s[kt][r] : -INFINITY;
          mt = fmaxf(mt, s[kt][r]);
        }
      }
      // reduce max across the 4 lanes sharing this q (lane bits 4-5)
      mt = fmaxf(mt, __shfl_xor(mt, 16, 64));
      mt = fmaxf(mt, __shfl_xor(mt, 32, 64));
      const float mnew = fmaxf(mreg[qt], mt);  // finite: own column in window
      const float corr = __expf(mreg[qt] - mnew);
      mreg[qt] = mnew;
      float ps = 0.f;
      #pragma unroll
      for (int kt = 0; kt < 4; ++kt) {
        #pragma unroll
        for (int r = 0; r < 4; ++r) {
          const float p = __expf(s[kt][r] - mnew);  // masked -> exp(-inf)=0
          s[kt][r] = p;
          ps += p;
        }
      }
      // reduce sum across the g-group
      ps += __shfl_xor(ps, 16, 64);
      ps += __shfl_xor(ps, 32, 64);
      lreg[qt] = lreg[qt] * corr + ps;
      #pragma unroll
      for (int dt = 0; dt < 3; ++dt) {
        ot[dt][qt][0] *= corr; ot[dt][qt][1] *= corr;
        ot[dt][qt][2] *= corr; ot[dt][qt][3] *= corr;
      }
      // pack P (bf16), write C-layout rows: plds[q][kt*16 + 4g .. +3]
      #pragma unroll
      for (int kt = 0; kt < 4; ++kt) {
        uint2 pk;
        pk.x = (unsigned int)f2bu(s[kt][0]) | ((unsigned int)f2bu(s[kt][1]) << 16);
        pk.y = (unsigned int)f2bu(s[kt][2]) | ((unsigned int)f2bu(s[kt][3]) << 16);
        *reinterpret_cast<uint2*>(&plds[(qt * 16 + ql) * 72 + kt * 16 + 4 * g]) = pk;
      }
    }

    // PV: O^T[dt][qt] += V^T · P^T  (B-frag: lane reads plds[q][32c+8g .. +7])
    #pragma unroll
    for (int qt = 0; qt < 4; ++qt) {
      #pragma unroll
      for (int c = 0; c < 2; ++c) {
        const short8v pf = *reinterpret_cast<const short8v*>(
            &plds[(qt * 16 + ql) * 72 + 32 * c + 8 * g]);
        #pragma unroll
        for (int dt = 0; dt < 3; ++dt)
          ot[dt][qt] = __builtin_amdgcn_mfma_f32_16x16x32_bf16(
              vf[dt][c], pf, ot[dt][qt], 0, 0, 0);
      }
    }
  }

  // epilogue: normalize, store O^T -> attn_out[(b, i*64+q)][h*48 + d]
  const int b = bh >> 3, h = bh & 7;
  #pragma unroll
  for (int qt = 0; qt < 4; ++qt) {
    const float inv = 1.0f / lreg[qt];
    unsigned short* orow =
        attn_out + (size_t)(b * 1024 + i * 64 + qt * 16 + ql) * 384 + h * 48;
    #pragma unroll
    for (int dt = 0; dt < 3; ++dt) {
      const int d0 = 16 * dt + 4 * g;
      unsigned int w0 = (unsigned int)f2bu(ot[dt][qt][0] * inv) |
                        ((unsigned int)f2bu(ot[dt][qt][1] * inv) << 16);
      unsigned int w1 = (unsigned int)f2bu(ot[dt][qt][2] * inv) |
                        ((unsigned int)f2bu(ot[dt][qt][3] * inv) << 16);
      *reinterpret_cast<unsigned int*>(orow + d0)     = w0;
      *reinterpret_cast<unsigned int*>(orow + d0 + 2) = w1;
    }
  }
}

extern "C" void kernel_launch(void* const* d_in, const int* in_sizes, int n_in,
                              void* d_out, int out_size, void* d_ws, size_t ws_size,
                              hipStream_t stream) {
  const float* x      = (const float*)d_in[0];
  const float* w_qkv  = (const float*)d_in[1];
  const float* w_proj = (const float*)d_in[2];
  const float* b_proj = (const float*)d_in[3];
  // d_in[4] (mask) unused: window is analytic (|di|<=3, |dj|<=5)

  const size_t T = 25165824;  // 32768*384*2 bytes
  char* ws = (char*)d_ws;
  unsigned short* xb    = (unsigned short*)ws;            // aliased with attn_out
  unsigned short* qws   = (unsigned short*)(ws + T);
  unsigned short* kws   = (unsigned short*)(ws + 2 * T);
  unsigned short* vtws  = (unsigned short*)(ws + 3 * T);  // [bh][48][1024]
  unsigned short* wqkvT = (unsigned short*)(ws + 4 * T);
  unsigned short* wpT   = (unsigned short*)(ws + 4 * T + 884736);
  unsigned short* attn_out = xb;  // xb dead after K1
  float* out = (float*)d_out;

  // K0: conversions
  cvt_f32_bf16<<<12288, 256, 0, stream>>>((const float4*)x, (ushort4v*)xb, 3145728);
  transpose_cvt<<<dim3(36, 12), dim3(32, 8), 0, stream>>>(w_qkv, wqkvT, 384, 1152);
  transpose_cvt<<<dim3(12, 12), dim3(32, 8), 0, stream>>>(w_proj, wpT, 384, 384);

  // K1: qkv GEMM (M=32768, K=384, N=1152) -> q/k [bh][s][48], v^T [bh][48][s]
  gemm_mfma<0><<<dim3(9, 256), 256, 0, stream>>>(xb, wqkvT, nullptr, nullptr,
                                                 qws, kws, vtws);
  // K2: MFMA local attention -> attn_out bf16 [B*S, 384]
  attn_mfma<<<dim3(4096), 64, 0, stream>>>(qws, kws, vtws, attn_out);
  // K3: out = attn_out @ w_proj + bias (N=384), f32 out
  gemm_mfma<1><<<dim3(3, 256), 256, 0, stream>>>(attn_out, wpT, b_proj, out,
                                                 nullptr, nullptr, nullptr);
}

// Round 12
// 133.577 us; speedup vs baseline: 1.4029x; 1.1684x over previous
//
#include <hip/hip_runtime.h>
#include <hip/hip_bf16.h>

// Local-window attention, B=32 S=1024(16x64) H=8 D=384/8=48, window 7x11.
// R12: attn — (a) band-skip: QK/softmax/pack only on tiles kt in [qt-1,qt+1]
//      (the |dj|<=5 band); plds zero-initialized once so PV reads exact zeros
//      elsewhere (bit-identical math, 37% less QK MFMA, ~40% less VALU).
//      (b) 4-wave workgroups (no barriers, per-wave plds slice) to lift the
//      ~3-waves/CU residency of 1-wave blocks toward the VGPR limit (12/CU).
//      K1/K3/cvt/transpose unchanged from R11 (passing).

typedef __attribute__((ext_vector_type(8))) unsigned short ushort8;
typedef __attribute__((ext_vector_type(4))) unsigned short ushort4v;
typedef __attribute__((ext_vector_type(8))) short short8v;
typedef __attribute__((ext_vector_type(4))) float floatx4;

__device__ __forceinline__ float bf2f(unsigned short u) {
  union { unsigned int i; float f; } x;
  x.i = ((unsigned int)u) << 16;
  return x.f;
}

__device__ __forceinline__ unsigned short f2bu(float f) {
  union { float f; unsigned int i; } x;
  x.f = f;
  unsigned int lsb = (x.i >> 16) & 1u;
  x.i += 0x7FFFu + lsb;  // RNE
  return (unsigned short)(x.i >> 16);
}

__device__ __forceinline__ void gload_lds16(const void* g, void* l) {
  __builtin_amdgcn_global_load_lds(
      (const __attribute__((address_space(1))) unsigned int*)g,
      (__attribute__((address_space(3))) unsigned int*)l, 16, 0, 0);
}

// ---------------- K0a: f32 -> bf16 ----------------
__global__ __launch_bounds__(256) void cvt_f32_bf16(
    const float4* __restrict__ in, ushort4v* __restrict__ out, int n4) {
  const int i = blockIdx.x * 256 + threadIdx.x;
  if (i < n4) {
    const float4 v = in[i];
    ushort4v o;
    o[0] = f2bu(v.x); o[1] = f2bu(v.y); o[2] = f2bu(v.z); o[3] = f2bu(v.w);
    out[i] = o;
  }
}

// ---------------- K0b/c: transpose f32 [R][C] -> bf16 [C][R] ----------------
__global__ __launch_bounds__(256) void transpose_cvt(
    const float* __restrict__ in, unsigned short* __restrict__ out, int R, int C) {
  __shared__ float t[32][33];
  const int c0 = blockIdx.x * 32, r0 = blockIdx.y * 32;
  const int tx = threadIdx.x, ty = threadIdx.y;
  #pragma unroll
  for (int rr = ty; rr < 32; rr += 8) t[rr][tx] = in[(size_t)(r0 + rr) * C + c0 + tx];
  __syncthreads();
  #pragma unroll
  for (int rr = ty; rr < 32; rr += 8)
    out[(size_t)(c0 + rr) * R + r0 + tx] = f2bu(t[tx][rr]);
}

// ---------------- MFMA GEMM, 2-tiles-per-barrier (eff. BK=64) ----------------
// Same as R11 (passing): pipelined K-loop; q/k scatter epilogue; V-blocks
// transpose through LDS and write vt coalesced.
template <int MODE>
__global__ __launch_bounds__(256) void gemm_mfma(
    const unsigned short* __restrict__ A,   // [M][384] bf16
    const unsigned short* __restrict__ Bt,  // [N][384] bf16 (= B^T)
    const float* __restrict__ bias, float* __restrict__ outf,
    unsigned short* __restrict__ qws, unsigned short* __restrict__ kws,
    unsigned short* __restrict__ vtws)
{
  __shared__ unsigned short smem[32768];  // 64KB: staging bufs / transpose tile
  const int tid = threadIdx.x;
  const int lane = tid & 63, w = tid >> 6;
  const int wm = w & 1, wn = w >> 1;

  const int nbx = gridDim.x;
  const int nwg = nbx * gridDim.y;
  const int bid = blockIdx.y * nbx + blockIdx.x;
  const int swz = (bid & 7) * (nwg >> 3) + (bid >> 3);
  const int n0 = (swz % nbx) * 128;
  const int m0 = (swz / nbx) * 128;

  floatx4 acc[4][4];
  #pragma unroll
  for (int mi = 0; mi < 4; ++mi)
    #pragma unroll
    for (int ni = 0; ni < 4; ++ni)
      acc[mi][ni] = (floatx4){0.f, 0.f, 0.f, 0.f};

  const int srow = w * 16 + (lane >> 2);
  const int kslot16 = (lane & 3) * 16;

  auto ASB = [&](int buf) -> unsigned short* { return smem + buf * 4096; };
  auto BSB = [&](int buf) -> unsigned short* { return smem + 16384 + buf * 4096; };

  auto STAGE = [&](int buf, int k0) {
    #pragma unroll
    for (int c = 0; c < 2; ++c) {
      const int r = c * 64 + srow;
      const int kb = kslot16 ^ ((r & 3) << 4);
      gload_lds16((const char*)A + (size_t)(m0 + r) * 768 + k0 * 2 + kb,
                  (char*)ASB(buf) + c * 4096 + w * 1024);
      gload_lds16((const char*)Bt + (size_t)(n0 + r) * 768 + k0 * 2 + kb,
                  (char*)BSB(buf) + c * 4096 + w * 1024);
    }
  };

  auto COMPUTE = [&](int buf) {
    short8v a[4], b[4];
    const int kgb = (lane >> 4) * 16;
    #pragma unroll
    for (int mi = 0; mi < 4; ++mi) {
      const int r = wm * 64 + mi * 16 + (lane & 15);
      a[mi] = *reinterpret_cast<const short8v*>(
          (const char*)ASB(buf) + r * 64 + (kgb ^ ((r & 3) << 4)));
    }
    #pragma unroll
    for (int ni = 0; ni < 4; ++ni) {
      const int r = wn * 64 + ni * 16 + (lane & 15);
      b[ni] = *reinterpret_cast<const short8v*>(
          (const char*)BSB(buf) + r * 64 + (kgb ^ ((r & 3) << 4)));
    }
    #pragma unroll
    for (int mi = 0; mi < 4; ++mi)
      #pragma unroll
      for (int ni = 0; ni < 4; ++ni)
        acc[mi][ni] = __builtin_amdgcn_mfma_f32_16x16x32_bf16(
            a[mi], b[ni], acc[mi][ni], 0, 0, 0);
  };

  STAGE(0, 0);
  STAGE(1, 32);

  #pragma unroll
  for (int s = 0; s < 6; ++s) {
    const int rb = (s & 1) * 2;
    const int sb = rb ^ 2;
    if (s < 5) {
      STAGE(sb, (2 * s + 2) * 32);
      STAGE(sb + 1, (2 * s + 3) * 32);
      asm volatile("s_waitcnt vmcnt(8)" ::: "memory");
    } else {
      asm volatile("s_waitcnt vmcnt(0)" ::: "memory");
    }
    __builtin_amdgcn_s_barrier();
    __builtin_amdgcn_s_setprio(1);
    COMPUTE(rb);
    COMPUTE(rb + 1);
    __builtin_amdgcn_s_setprio(0);
    asm volatile("s_waitcnt lgkmcnt(0)" ::: "memory");
    __builtin_amdgcn_s_barrier();
  }

  const int col_l = lane & 15;
  const int row_l = (lane >> 4) * 4;

  if (MODE == 0) {
    const float QSCALE = 0.14433756729740643f;  // 1/sqrt(48)
    const int which = n0 / 384;  // uniform per block (384 | 128*{0,3,6})
    if (which < 2) {
      unsigned short* dstb = (which == 0) ? qws : kws;
      const float scale = (which == 0) ? QSCALE : 1.f;
      #pragma unroll
      for (int ni = 0; ni < 4; ++ni) {
        const int cg = n0 + wn * 64 + ni * 16 + col_l;
        const int rem = cg - which * 384;
        const int h = rem / 48;
        const int d = rem - h * 48;
        #pragma unroll
        for (int mi = 0; mi < 4; ++mi) {
          #pragma unroll
          for (int reg = 0; reg < 4; ++reg) {
            const int r = m0 + wm * 64 + mi * 16 + row_l + reg;
            const int bb = r >> 10, s = r & 1023;
            dstb[(((size_t)(bb * 8 + h)) * 1024 + s) * 48 + d] =
                f2bu(acc[mi][ni][reg] * scale);
          }
        }
      }
    } else {
      // V: transpose C-tile through LDS, coalesced vt writes (R11-verified)
      unsigned short* T = smem;  // 128*136 shorts, aliases dead staging smem
      #pragma unroll
      for (int ni = 0; ni < 4; ++ni) {
        const int col = wn * 64 + ni * 16 + col_l;
        #pragma unroll
        for (int mi = 0; mi < 4; ++mi) {
          const int rowb = wm * 64 + mi * 16 + row_l;
          #pragma unroll
          for (int reg = 0; reg < 4; ++reg)
            T[col * 136 + rowb + reg] = f2bu(acc[mi][ni][reg]);
        }
      }
      __syncthreads();
      const int col = tid >> 1, half = tid & 1;
      const int cg = n0 + col;
      const int rem = cg - 768;
      const int h = rem / 48, d = rem - h * 48;
      const int bb = m0 >> 10;
      const int s0 = (m0 & 1023) + half * 64;
      unsigned short* dst =
          vtws + (((size_t)(bb * 8 + h)) * 48 + d) * 1024 + s0;
      const unsigned short* src = T + col * 136 + half * 64;
      #pragma unroll
      for (int j = 0; j < 8; ++j)
        *reinterpret_cast<ushort8*>(dst + j * 8) =
            *reinterpret_cast<const ushort8*>(src + j * 8);
    }
  } else {
    #pragma unroll
    for (int ni = 0; ni < 4; ++ni) {
      const int cg = n0 + wn * 64 + ni * 16 + col_l;
      const float bv = bias[cg];
      #pragma unroll
      for (int mi = 0; mi < 4; ++mi) {
        #pragma unroll
        for (int reg = 0; reg < 4; ++reg) {
          const int r = m0 + wm * 64 + mi * 16 + row_l + reg;
          outf[(size_t)r * 384 + cg] = acc[mi][ni][reg] + bv;
        }
      }
    }
  }
}

// ---------------- K2: MFMA local attention, band-skip + 4-wave blocks ----------
// 1024 blocks x 256 threads; wave w handles task swz*4+w (same bh, adjacent i).
// No barriers — per-wave plds slice (9KB). Band-skip: only kt in [qt-1,qt+1]
// computed/exp'd/packed; plds zeroed once so PV reads exact zeros elsewhere.
__global__ __launch_bounds__(256) void attn_mfma(
    const unsigned short* __restrict__ qws,  // [bh][1024][48]
    const unsigned short* __restrict__ kws,  // [bh][1024][48]
    const unsigned short* __restrict__ vt,   // [bh][48][1024]
    unsigned short* __restrict__ attn_out)   // [b*1024][384] bf16
{
  __shared__ unsigned short plds_all[4 * 64 * 72];

  const int tid = threadIdx.x;
  const int w = tid >> 6;
  const int lane = tid & 63;
  const int blk = blockIdx.x;
  const int sw = ((blk & 7) << 7) | (blk >> 3);  // 1024 % 8 == 0
  const int task = sw * 4 + w;
  const int i  = task & 15;
  const int bh = task >> 4;
  const int ql = lane & 15;
  const int g  = lane >> 4;

  unsigned short* plds = plds_all + w * 4608;  // 64*72 per wave

  // zero plds once: band-external tiles stay 0 forever -> PV adds exact zeros
  {
    const uint4 zz = make_uint4(0, 0, 0, 0);
    #pragma unroll
    for (int z = 0; z < 9; ++z)
      reinterpret_cast<uint4*>(plds)[lane + z * 64] = zz;
  }

  const unsigned short* qbase = qws + (size_t)bh * 1024 * 48;
  const unsigned short* kbase = kws + (size_t)bh * 1024 * 48;
  const unsigned short* vbase = vt  + (size_t)bh * 48 * 1024;

  const short8v zfrag = (short8v){0, 0, 0, 0, 0, 0, 0, 0};

  // Q fragments [qt][kstep]; D=48 zero-padded to 64 (kstep1, g>=2 -> 0)
  short8v qf[4][2];
  #pragma unroll
  for (int qt = 0; qt < 4; ++qt) {
    const unsigned short* qrow = qbase + (size_t)(i * 64 + qt * 16 + ql) * 48;
    qf[qt][0] = *reinterpret_cast<const short8v*>(qrow + 8 * g);
    qf[qt][1] = (g < 2) ? *reinterpret_cast<const short8v*>(qrow + 32 + 8 * g)
                        : zfrag;
  }

  floatx4 ot[3][4];
  #pragma unroll
  for (int dt = 0; dt < 3; ++dt)
    #pragma unroll
    for (int qt = 0; qt < 4; ++qt)
      ot[dt][qt] = (floatx4){0.f, 0.f, 0.f, 0.f};
  float mreg[4] = {-INFINITY, -INFINITY, -INFINITY, -INFINITY};
  float lreg[4] = {0.f, 0.f, 0.f, 0.f};

  const int ki0 = (i - 3 < 0) ? 0 : i - 3;
  const int ki1 = (i + 3 > 15) ? 15 : i + 3;

  for (int ki = ki0; ki <= ki1; ++ki) {
    // K fragments [kt][kstep]
    short8v kf[4][2];
    #pragma unroll
    for (int kt = 0; kt < 4; ++kt) {
      const unsigned short* krow = kbase + (size_t)(ki * 64 + kt * 16 + ql) * 48;
      kf[kt][0] = *reinterpret_cast<const short8v*>(krow + 8 * g);
      kf[kt][1] = (g < 2) ? *reinterpret_cast<const short8v*>(krow + 32 + 8 * g)
                          : zfrag;
    }
    // V^T fragments [dt][chunk]
    short8v vf[3][2];
    #pragma unroll
    for (int dt = 0; dt < 3; ++dt)
      #pragma unroll
      for (int c = 0; c < 2; ++c)
        vf[dt][c] = *reinterpret_cast<const short8v*>(
            vbase + (size_t)(16 * dt + ql) * 1024 + ki * 64 + 32 * c + 8 * g);

    // per q-tile: banded QK^T, mask, g-group-reduced online softmax, P -> LDS
    #pragma unroll
    for (int qt = 0; qt < 4; ++qt) {
      const int kts = (qt == 0) ? 0 : qt - 1;
      const int kte = (qt == 3) ? 3 : qt + 1;
      floatx4 s[4];
      #pragma unroll
      for (int kt = 0; kt < 4; ++kt) {
        if (kt < kts || kt > kte) continue;
        s[kt] = __builtin_amdgcn_mfma_f32_16x16x32_bf16(
            kf[kt][0], qf[qt][0], (floatx4){0.f, 0.f, 0.f, 0.f}, 0, 0, 0);
        s[kt] = __builtin_amdgcn_mfma_f32_16x16x32_bf16(
            kf[kt][1], qf[qt][1], s[kt], 0, 0, 0);
      }
      const int qcol = qt * 16 + ql;
      float mt = -INFINITY;
      #pragma unroll
      for (int kt = 0; kt < 4; ++kt) {
        if (kt < kts || kt > kte) continue;
        #pragma unroll
        for (int r = 0; r < 4; ++r) {
          const int delta = kt * 16 + 4 * g + r - qcol;
          const bool ok = (delta <= 5) && (delta >= -5);
          s[kt][r] = ok ? s[kt][r] : -INFINITY;
          mt = fmaxf(mt, s[kt][r]);
        }
      }
      mt = fmaxf(mt, __shfl_xor(mt, 16, 64));
      mt = fmaxf(mt, __shfl_xor(mt, 32, 64));
      const float mnew = fmaxf(mreg[qt], mt);
      const float corr = __expf(mreg[qt] - mnew);
      mreg[qt] = mnew;
      float ps = 0.f;
      #pragma unroll
      for (int kt = 0; kt < 4; ++kt) {
        if (kt < kts || kt > kte) continue;
        #pragma unroll
        for (int r = 0; r < 4; ++r) {
          const float p = __expf(s[kt][r] - mnew);
          s[kt][r] = p;
          ps += p;
        }
      }
      ps += __shfl_xor(ps, 16, 64);
      ps += __shfl_xor(ps, 32, 64);
      lreg[qt] = lreg[qt] * corr + ps;
      #pragma unroll
      for (int dt = 0; dt < 3; ++dt) {
        ot[dt][qt][0] *= corr; ot[dt][qt][1] *= corr;
        ot[dt][qt][2] *= corr; ot[dt][qt][3] *= corr;
      }
      #pragma unroll
      for (int kt = 0; kt < 4; ++kt) {
        if (kt < kts || kt > kte) continue;
        uint2 pk;
        pk.x = (unsigned int)f2bu(s[kt][0]) | ((unsigned int)f2bu(s[kt][1]) << 16);
        pk.y = (unsigned int)f2bu(s[kt][2]) | ((unsigned int)f2bu(s[kt][3]) << 16);
        *reinterpret_cast<uint2*>(&plds[(qt * 16 + ql) * 72 + kt * 16 + 4 * g]) = pk;
      }
    }

    // PV: O^T[dt][qt] += V^T · P^T  (reads full 64-k row; non-band = 0)
    #pragma unroll
    for (int qt = 0; qt < 4; ++qt) {
      #pragma unroll
      for (int c = 0; c < 2; ++c) {
        const short8v pf = *reinterpret_cast<const short8v*>(
            &plds[(qt * 16 + ql) * 72 + 32 * c + 8 * g]);
        #pragma unroll
        for (int dt = 0; dt < 3; ++dt)
          ot[dt][qt] = __builtin_amdgcn_mfma_f32_16x16x32_bf16(
              vf[dt][c], pf, ot[dt][qt], 0, 0, 0);
      }
    }
  }

  // epilogue: normalize, store O^T -> attn_out[(b, i*64+q)][h*48 + d]
  const int b = bh >> 3, h = bh & 7;
  #pragma unroll
  for (int qt = 0; qt < 4; ++qt) {
    const float inv = 1.0f / lreg[qt];
    unsigned short* orow =
        attn_out + (size_t)(b * 1024 + i * 64 + qt * 16 + ql) * 384 + h * 48;
    #pragma unroll
    for (int dt = 0; dt < 3; ++dt) {
      const int d0 = 16 * dt + 4 * g;
      unsigned int w0 = (unsigned int)f2bu(ot[dt][qt][0] * inv) |
                        ((unsigned int)f2bu(ot[dt][qt][1] * inv) << 16);
      unsigned int w1 = (unsigned int)f2bu(ot[dt][qt][2] * inv) |
                        ((unsigned int)f2bu(ot[dt][qt][3] * inv) << 16);
      *reinterpret_cast<unsigned int*>(orow + d0)     = w0;
      *reinterpret_cast<unsigned int*>(orow + d0 + 2) = w1;
    }
  }
}

extern "C" void kernel_launch(void* const* d_in, const int* in_sizes, int n_in,
                              void* d_out, int out_size, void* d_ws, size_t ws_size,
                              hipStream_t stream) {
  const float* x      = (const float*)d_in[0];
  const float* w_qkv  = (const float*)d_in[1];
  const float* w_proj = (const float*)d_in[2];
  const float* b_proj = (const float*)d_in[3];
  // d_in[4] (mask) unused: window is analytic (|di|<=3, |dj|<=5)

  const size_t T = 25165824;  // 32768*384*2 bytes
  char* ws = (char*)d_ws;
  unsigned short* xb    = (unsigned short*)ws;            // aliased with attn_out
  unsigned short* qws   = (unsigned short*)(ws + T);
  unsigned short* kws   = (unsigned short*)(ws + 2 * T);
  unsigned short* vtws  = (unsigned short*)(ws + 3 * T);  // [bh][48][1024]
  unsigned short* wqkvT = (unsigned short*)(ws + 4 * T);
  unsigned short* wpT   = (unsigned short*)(ws + 4 * T + 884736);
  unsigned short* attn_out = xb;  // xb dead after K1
  float* out = (float*)d_out;

  // K0: conversions
  cvt_f32_bf16<<<12288, 256, 0, stream>>>((const float4*)x, (ushort4v*)xb, 3145728);
  transpose_cvt<<<dim3(36, 12), dim3(32, 8), 0, stream>>>(w_qkv, wqkvT, 384, 1152);
  transpose_cvt<<<dim3(12, 12), dim3(32, 8), 0, stream>>>(w_proj, wpT, 384, 384);

  // K1: qkv GEMM (M=32768, K=384, N=1152) -> q/k [bh][s][48], v^T [bh][48][s]
  gemm_mfma<0><<<dim3(9, 256), 256, 0, stream>>>(xb, wqkvT, nullptr, nullptr,
                                                 qws, kws, vtws);
  // K2: MFMA local attention -> attn_out bf16 [B*S, 384]
  attn_mfma<<<dim3(1024), 256, 0, stream>>>(qws, kws, vtws, attn_out);
  // K3: out = attn_out @ w_proj + bias (N=384), f32 out
  gemm_mfma<1><<<dim3(3, 256), 256, 0, stream>>>(attn_out, wpT, b_proj, out,
                                                 nullptr, nullptr, nullptr);
}

// Round 13
// 132.219 us; speedup vs baseline: 1.4173x; 1.0103x over previous
//
#include <hip/hip_runtime.h>
#include <hip/hip_bf16.h>

// Local-window attention, B=32 S=1024(16x64) H=8 D=384/8=48, window 7x11.
// R13: attn — defer-max (T13): skip max-reduce shuffles + corr exp + O/l
//      rescale when __all(lane-band-max - m <= 8); P bounded by e^8 (bf16-safe,
//      P and l consistently scaled). First iter always rescales (m=-inf).
//      + s_setprio(1) around the PV MFMA cluster (T5; multi-wave no-barrier
//      structure = m191's +4-7% case). K1/K3/cvt/transpose = R12 (passing).

typedef __attribute__((ext_vector_type(8))) unsigned short ushort8;
typedef __attribute__((ext_vector_type(4))) unsigned short ushort4v;
typedef __attribute__((ext_vector_type(8))) short short8v;
typedef __attribute__((ext_vector_type(4))) float floatx4;

__device__ __forceinline__ float bf2f(unsigned short u) {
  union { unsigned int i; float f; } x;
  x.i = ((unsigned int)u) << 16;
  return x.f;
}

__device__ __forceinline__ unsigned short f2bu(float f) {
  union { float f; unsigned int i; } x;
  x.f = f;
  unsigned int lsb = (x.i >> 16) & 1u;
  x.i += 0x7FFFu + lsb;  // RNE
  return (unsigned short)(x.i >> 16);
}

__device__ __forceinline__ void gload_lds16(const void* g, void* l) {
  __builtin_amdgcn_global_load_lds(
      (const __attribute__((address_space(1))) unsigned int*)g,
      (__attribute__((address_space(3))) unsigned int*)l, 16, 0, 0);
}

// ---------------- K0a: f32 -> bf16 ----------------
__global__ __launch_bounds__(256) void cvt_f32_bf16(
    const float4* __restrict__ in, ushort4v* __restrict__ out, int n4) {
  const int i = blockIdx.x * 256 + threadIdx.x;
  if (i < n4) {
    const float4 v = in[i];
    ushort4v o;
    o[0] = f2bu(v.x); o[1] = f2bu(v.y); o[2] = f2bu(v.z); o[3] = f2bu(v.w);
    out[i] = o;
  }
}

// ---------------- K0b/c: transpose f32 [R][C] -> bf16 [C][R] ----------------
__global__ __launch_bounds__(256) void transpose_cvt(
    const float* __restrict__ in, unsigned short* __restrict__ out, int R, int C) {
  __shared__ float t[32][33];
  const int c0 = blockIdx.x * 32, r0 = blockIdx.y * 32;
  const int tx = threadIdx.x, ty = threadIdx.y;
  #pragma unroll
  for (int rr = ty; rr < 32; rr += 8) t[rr][tx] = in[(size_t)(r0 + rr) * C + c0 + tx];
  __syncthreads();
  #pragma unroll
  for (int rr = ty; rr < 32; rr += 8)
    out[(size_t)(c0 + rr) * R + r0 + tx] = f2bu(t[tx][rr]);
}

// ---------------- MFMA GEMM, 2-tiles-per-barrier (eff. BK=64) ----------------
// Same as R11/R12 (passing).
template <int MODE>
__global__ __launch_bounds__(256) void gemm_mfma(
    const unsigned short* __restrict__ A,   // [M][384] bf16
    const unsigned short* __restrict__ Bt,  // [N][384] bf16 (= B^T)
    const float* __restrict__ bias, float* __restrict__ outf,
    unsigned short* __restrict__ qws, unsigned short* __restrict__ kws,
    unsigned short* __restrict__ vtws)
{
  __shared__ unsigned short smem[32768];
  const int tid = threadIdx.x;
  const int lane = tid & 63, w = tid >> 6;
  const int wm = w & 1, wn = w >> 1;

  const int nbx = gridDim.x;
  const int nwg = nbx * gridDim.y;
  const int bid = blockIdx.y * nbx + blockIdx.x;
  const int swz = (bid & 7) * (nwg >> 3) + (bid >> 3);
  const int n0 = (swz % nbx) * 128;
  const int m0 = (swz / nbx) * 128;

  floatx4 acc[4][4];
  #pragma unroll
  for (int mi = 0; mi < 4; ++mi)
    #pragma unroll
    for (int ni = 0; ni < 4; ++ni)
      acc[mi][ni] = (floatx4){0.f, 0.f, 0.f, 0.f};

  const int srow = w * 16 + (lane >> 2);
  const int kslot16 = (lane & 3) * 16;

  auto ASB = [&](int buf) -> unsigned short* { return smem + buf * 4096; };
  auto BSB = [&](int buf) -> unsigned short* { return smem + 16384 + buf * 4096; };

  auto STAGE = [&](int buf, int k0) {
    #pragma unroll
    for (int c = 0; c < 2; ++c) {
      const int r = c * 64 + srow;
      const int kb = kslot16 ^ ((r & 3) << 4);
      gload_lds16((const char*)A + (size_t)(m0 + r) * 768 + k0 * 2 + kb,
                  (char*)ASB(buf) + c * 4096 + w * 1024);
      gload_lds16((const char*)Bt + (size_t)(n0 + r) * 768 + k0 * 2 + kb,
                  (char*)BSB(buf) + c * 4096 + w * 1024);
    }
  };

  auto COMPUTE = [&](int buf) {
    short8v a[4], b[4];
    const int kgb = (lane >> 4) * 16;
    #pragma unroll
    for (int mi = 0; mi < 4; ++mi) {
      const int r = wm * 64 + mi * 16 + (lane & 15);
      a[mi] = *reinterpret_cast<const short8v*>(
          (const char*)ASB(buf) + r * 64 + (kgb ^ ((r & 3) << 4)));
    }
    #pragma unroll
    for (int ni = 0; ni < 4; ++ni) {
      const int r = wn * 64 + ni * 16 + (lane & 15);
      b[ni] = *reinterpret_cast<const short8v*>(
          (const char*)BSB(buf) + r * 64 + (kgb ^ ((r & 3) << 4)));
    }
    #pragma unroll
    for (int mi = 0; mi < 4; ++mi)
      #pragma unroll
      for (int ni = 0; ni < 4; ++ni)
        acc[mi][ni] = __builtin_amdgcn_mfma_f32_16x16x32_bf16(
            a[mi], b[ni], acc[mi][ni], 0, 0, 0);
  };

  STAGE(0, 0);
  STAGE(1, 32);

  #pragma unroll
  for (int s = 0; s < 6; ++s) {
    const int rb = (s & 1) * 2;
    const int sb = rb ^ 2;
    if (s < 5) {
      STAGE(sb, (2 * s + 2) * 32);
      STAGE(sb + 1, (2 * s + 3) * 32);
      asm volatile("s_waitcnt vmcnt(8)" ::: "memory");
    } else {
      asm volatile("s_waitcnt vmcnt(0)" ::: "memory");
    }
    __builtin_amdgcn_s_barrier();
    __builtin_amdgcn_s_setprio(1);
    COMPUTE(rb);
    COMPUTE(rb + 1);
    __builtin_amdgcn_s_setprio(0);
    asm volatile("s_waitcnt lgkmcnt(0)" ::: "memory");
    __builtin_amdgcn_s_barrier();
  }

  const int col_l = lane & 15;
  const int row_l = (lane >> 4) * 4;

  if (MODE == 0) {
    const float QSCALE = 0.14433756729740643f;  // 1/sqrt(48)
    const int which = n0 / 384;
    if (which < 2) {
      unsigned short* dstb = (which == 0) ? qws : kws;
      const float scale = (which == 0) ? QSCALE : 1.f;
      #pragma unroll
      for (int ni = 0; ni < 4; ++ni) {
        const int cg = n0 + wn * 64 + ni * 16 + col_l;
        const int rem = cg - which * 384;
        const int h = rem / 48;
        const int d = rem - h * 48;
        #pragma unroll
        for (int mi = 0; mi < 4; ++mi) {
          #pragma unroll
          for (int reg = 0; reg < 4; ++reg) {
            const int r = m0 + wm * 64 + mi * 16 + row_l + reg;
            const int bb = r >> 10, s = r & 1023;
            dstb[(((size_t)(bb * 8 + h)) * 1024 + s) * 48 + d] =
                f2bu(acc[mi][ni][reg] * scale);
          }
        }
      }
    } else {
      unsigned short* T = smem;  // 128*136 shorts, aliases dead staging smem
      #pragma unroll
      for (int ni = 0; ni < 4; ++ni) {
        const int col = wn * 64 + ni * 16 + col_l;
        #pragma unroll
        for (int mi = 0; mi < 4; ++mi) {
          const int rowb = wm * 64 + mi * 16 + row_l;
          #pragma unroll
          for (int reg = 0; reg < 4; ++reg)
            T[col * 136 + rowb + reg] = f2bu(acc[mi][ni][reg]);
        }
      }
      __syncthreads();
      const int col = tid >> 1, half = tid & 1;
      const int cg = n0 + col;
      const int rem = cg - 768;
      const int h = rem / 48, d = rem - h * 48;
      const int bb = m0 >> 10;
      const int s0 = (m0 & 1023) + half * 64;
      unsigned short* dst =
          vtws + (((size_t)(bb * 8 + h)) * 48 + d) * 1024 + s0;
      const unsigned short* src = T + col * 136 + half * 64;
      #pragma unroll
      for (int j = 0; j < 8; ++j)
        *reinterpret_cast<ushort8*>(dst + j * 8) =
            *reinterpret_cast<const ushort8*>(src + j * 8);
    }
  } else {
    #pragma unroll
    for (int ni = 0; ni < 4; ++ni) {
      const int cg = n0 + wn * 64 + ni * 16 + col_l;
      const float bv = bias[cg];
      #pragma unroll
      for (int mi = 0; mi < 4; ++mi) {
        #pragma unroll
        for (int reg = 0; reg < 4; ++reg) {
          const int r = m0 + wm * 64 + mi * 16 + row_l + reg;
          outf[(size_t)r * 384 + cg] = acc[mi][ni][reg] + bv;
        }
      }
    }
  }
}

// ---------------- K2: MFMA local attention, band-skip + defer-max ----------
__global__ __launch_bounds__(256) void attn_mfma(
    const unsigned short* __restrict__ qws,  // [bh][1024][48]
    const unsigned short* __restrict__ kws,  // [bh][1024][48]
    const unsigned short* __restrict__ vt,   // [bh][48][1024]
    unsigned short* __restrict__ attn_out)   // [b*1024][384] bf16
{
  __shared__ unsigned short plds_all[4 * 64 * 72];

  const int tid = threadIdx.x;
  const int w = tid >> 6;
  const int lane = tid & 63;
  const int blk = blockIdx.x;
  const int sw = ((blk & 7) << 7) | (blk >> 3);  // 1024 % 8 == 0
  const int task = sw * 4 + w;
  const int i  = task & 15;
  const int bh = task >> 4;
  const int ql = lane & 15;
  const int g  = lane >> 4;

  unsigned short* plds = plds_all + w * 4608;  // 64*72 per wave

  // zero plds once: band-external tiles stay 0 forever -> PV adds exact zeros
  {
    const uint4 zz = make_uint4(0, 0, 0, 0);
    #pragma unroll
    for (int z = 0; z < 9; ++z)
      reinterpret_cast<uint4*>(plds)[lane + z * 64] = zz;
  }

  const unsigned short* qbase = qws + (size_t)bh * 1024 * 48;
  const unsigned short* kbase = kws + (size_t)bh * 1024 * 48;
  const unsigned short* vbase = vt  + (size_t)bh * 48 * 1024;

  const short8v zfrag = (short8v){0, 0, 0, 0, 0, 0, 0, 0};

  // Q fragments [qt][kstep]; D=48 zero-padded to 64 (kstep1, g>=2 -> 0)
  short8v qf[4][2];
  #pragma unroll
  for (int qt = 0; qt < 4; ++qt) {
    const unsigned short* qrow = qbase + (size_t)(i * 64 + qt * 16 + ql) * 48;
    qf[qt][0] = *reinterpret_cast<const short8v*>(qrow + 8 * g);
    qf[qt][1] = (g < 2) ? *reinterpret_cast<const short8v*>(qrow + 32 + 8 * g)
                        : zfrag;
  }

  floatx4 ot[3][4];
  #pragma unroll
  for (int dt = 0; dt < 3; ++dt)
    #pragma unroll
    for (int qt = 0; qt < 4; ++qt)
      ot[dt][qt] = (floatx4){0.f, 0.f, 0.f, 0.f};
  float mreg[4] = {-INFINITY, -INFINITY, -INFINITY, -INFINITY};
  float lreg[4] = {0.f, 0.f, 0.f, 0.f};

  const int ki0 = (i - 3 < 0) ? 0 : i - 3;
  const int ki1 = (i + 3 > 15) ? 15 : i + 3;

  for (int ki = ki0; ki <= ki1; ++ki) {
    // K fragments [kt][kstep]
    short8v kf[4][2];
    #pragma unroll
    for (int kt = 0; kt < 4; ++kt) {
      const unsigned short* krow = kbase + (size_t)(ki * 64 + kt * 16 + ql) * 48;
      kf[kt][0] = *reinterpret_cast<const short8v*>(krow + 8 * g);
      kf[kt][1] = (g < 2) ? *reinterpret_cast<const short8v*>(krow + 32 + 8 * g)
                          : zfrag;
    }
    // V^T fragments [dt][chunk]
    short8v vf[3][2];
    #pragma unroll
    for (int dt = 0; dt < 3; ++dt)
      #pragma unroll
      for (int c = 0; c < 2; ++c)
        vf[dt][c] = *reinterpret_cast<const short8v*>(
            vbase + (size_t)(16 * dt + ql) * 1024 + ki * 64 + 32 * c + 8 * g);

    // per q-tile: banded QK^T, mask, defer-max online softmax, P -> LDS
    #pragma unroll
    for (int qt = 0; qt < 4; ++qt) {
      const int kts = (qt == 0) ? 0 : qt - 1;
      const int kte = (qt == 3) ? 3 : qt + 1;
      floatx4 s[4];
      #pragma unroll
      for (int kt = 0; kt < 4; ++kt) {
        if (kt < kts || kt > kte) continue;
        s[kt] = __builtin_amdgcn_mfma_f32_16x16x32_bf16(
            kf[kt][0], qf[qt][0], (floatx4){0.f, 0.f, 0.f, 0.f}, 0, 0, 0);
        s[kt] = __builtin_amdgcn_mfma_f32_16x16x32_bf16(
            kf[kt][1], qf[qt][1], s[kt], 0, 0, 0);
      }
      const int qcol = qt * 16 + ql;
      float pmax = -INFINITY;  // lane-local band max
      #pragma unroll
      for (int kt = 0; kt < 4; ++kt) {
        if (kt < kts || kt > kte) continue;
        #pragma unroll
        for (int r = 0; r < 4; ++r) {
          const int delta = kt * 16 + 4 * g + r - qcol;
          const bool ok = (delta <= 5) && (delta >= -5);
          s[kt][r] = ok ? s[kt][r] : -INFINITY;
          pmax = fmaxf(pmax, s[kt][r]);
        }
      }
      // defer-max: only rescale when some lane's band max exceeds m + 8.
      // (first ki: m=-inf -> condition false -> always rescales/initializes)
      if (!__all(pmax - mreg[qt] <= 8.0f)) {
        float mt = fmaxf(pmax, __shfl_xor(pmax, 16, 64));
        mt = fmaxf(mt, __shfl_xor(mt, 32, 64));
        const float mnew = fmaxf(mreg[qt], mt);
        const float corr = __expf(mreg[qt] - mnew);  // exp(-inf)=0 first time
        lreg[qt] *= corr;
        #pragma unroll
        for (int dt = 0; dt < 3; ++dt) {
          ot[dt][qt][0] *= corr; ot[dt][qt][1] *= corr;
          ot[dt][qt][2] *= corr; ot[dt][qt][3] *= corr;
        }
        mreg[qt] = mnew;
      }
      float ps = 0.f;
      #pragma unroll
      for (int kt = 0; kt < 4; ++kt) {
        if (kt < kts || kt > kte) continue;
        #pragma unroll
        for (int r = 0; r < 4; ++r) {
          const float p = __expf(s[kt][r] - mreg[qt]);  // bounded by e^8
          s[kt][r] = p;
          ps += p;
        }
      }
      ps += __shfl_xor(ps, 16, 64);
      ps += __shfl_xor(ps, 32, 64);
      lreg[qt] += ps;
      #pragma unroll
      for (int kt = 0; kt < 4; ++kt) {
        if (kt < kts || kt > kte) continue;
        uint2 pk;
        pk.x = (unsigned int)f2bu(s[kt][0]) | ((unsigned int)f2bu(s[kt][1]) << 16);
        pk.y = (unsigned int)f2bu(s[kt][2]) | ((unsigned int)f2bu(s[kt][3]) << 16);
        *reinterpret_cast<uint2*>(&plds[(qt * 16 + ql) * 72 + kt * 16 + 4 * g]) = pk;
      }
    }

    // PV: O^T[dt][qt] += V^T · P^T  (reads full 64-k row; non-band = 0)
    __builtin_amdgcn_s_setprio(1);
    #pragma unroll
    for (int qt = 0; qt < 4; ++qt) {
      #pragma unroll
      for (int c = 0; c < 2; ++c) {
        const short8v pf = *reinterpret_cast<const short8v*>(
            &plds[(qt * 16 + ql) * 72 + 32 * c + 8 * g]);
        #pragma unroll
        for (int dt = 0; dt < 3; ++dt)
          ot[dt][qt] = __builtin_amdgcn_mfma_f32_16x16x32_bf16(
              vf[dt][c], pf, ot[dt][qt], 0, 0, 0);
      }
    }
    __builtin_amdgcn_s_setprio(0);
  }

  // epilogue: normalize, store O^T -> attn_out[(b, i*64+q)][h*48 + d]
  const int b = bh >> 3, h = bh & 7;
  #pragma unroll
  for (int qt = 0; qt < 4; ++qt) {
    const float inv = 1.0f / lreg[qt];
    unsigned short* orow =
        attn_out + (size_t)(b * 1024 + i * 64 + qt * 16 + ql) * 384 + h * 48;
    #pragma unroll
    for (int dt = 0; dt < 3; ++dt) {
      const int d0 = 16 * dt + 4 * g;
      unsigned int w0 = (unsigned int)f2bu(ot[dt][qt][0] * inv) |
                        ((unsigned int)f2bu(ot[dt][qt][1] * inv) << 16);
      unsigned int w1 = (unsigned int)f2bu(ot[dt][qt][2] * inv) |
                        ((unsigned int)f2bu(ot[dt][qt][3] * inv) << 16);
      *reinterpret_cast<unsigned int*>(orow + d0)     = w0;
      *reinterpret_cast<unsigned int*>(orow + d0 + 2) = w1;
    }
  }
}

extern "C" void kernel_launch(void* const* d_in, const int* in_sizes, int n_in,
                              void* d_out, int out_size, void* d_ws, size_t ws_size,
                              hipStream_t stream) {
  const float* x      = (const float*)d_in[0];
  const float* w_qkv  = (const float*)d_in[1];
  const float* w_proj = (const float*)d_in[2];
  const float* b_proj = (const float*)d_in[3];
  // d_in[4] (mask) unused: window is analytic (|di|<=3, |dj|<=5)

  const size_t T = 25165824;  // 32768*384*2 bytes
  char* ws = (char*)d_ws;
  unsigned short* xb    = (unsigned short*)ws;            // aliased with attn_out
  unsigned short* qws   = (unsigned short*)(ws + T);
  unsigned short* kws   = (unsigned short*)(ws + 2 * T);
  unsigned short* vtws  = (unsigned short*)(ws + 3 * T);  // [bh][48][1024]
  unsigned short* wqkvT = (unsigned short*)(ws + 4 * T);
  unsigned short* wpT   = (unsigned short*)(ws + 4 * T + 884736);
  unsigned short* attn_out = xb;  // xb dead after K1
  float* out = (float*)d_out;

  // K0: conversions
  cvt_f32_bf16<<<12288, 256, 0, stream>>>((const float4*)x, (ushort4v*)xb, 3145728);
  transpose_cvt<<<dim3(36, 12), dim3(32, 8), 0, stream>>>(w_qkv, wqkvT, 384, 1152);
  transpose_cvt<<<dim3(12, 12), dim3(32, 8), 0, stream>>>(w_proj, wpT, 384, 384);

  // K1: qkv GEMM (M=32768, K=384, N=1152) -> q/k [bh][s][48], v^T [bh][48][s]
  gemm_mfma<0><<<dim3(9, 256), 256, 0, stream>>>(xb, wqkvT, nullptr, nullptr,
                                                 qws, kws, vtws);
  // K2: MFMA local attention -> attn_out bf16 [B*S, 384]
  attn_mfma<<<dim3(1024), 256, 0, stream>>>(qws, kws, vtws, attn_out);
  // K3: out = attn_out @ w_proj + bias (N=384), f32 out
  gemm_mfma<1><<<dim3(3, 256), 256, 0, stream>>>(attn_out, wpT, b_proj, out,
                                                 nullptr, nullptr, nullptr);
}